// Round 6
// baseline (1434.256 us; speedup 1.0000x reference)
//
#include <hip/hip_runtime.h>
#include <hip/hip_bf16.h>

#define N 4096
#define D 512
#define LOG2E 1.4426950408889634f
#define LN2   0.6931471805599453f
#define LA2   (-12.0f)                 // -log2(4096)
#define VADD  15.635532333438686f      // -(la + lb + 1)

typedef unsigned short u16;
typedef unsigned char u8;
typedef __attribute__((ext_vector_type(8))) short short8;
typedef __attribute__((ext_vector_type(8))) unsigned short ushort8;
typedef __attribute__((ext_vector_type(4))) float fvec4;
typedef __attribute__((ext_vector_type(2))) unsigned int uivec2;
typedef __attribute__((ext_vector_type(4))) unsigned int uivec4;

static __device__ __forceinline__ float bf2f(unsigned short u) {
    union { unsigned int i; float f; } c;
    c.i = ((unsigned int)u) << 16;
    return c.f;
}

static __device__ __forceinline__ unsigned short f2bf(float x) {
    __hip_bfloat16 h = __float2bfloat16(x);  // RNE
    unsigned short u;
    __builtin_memcpy(&u, &h, 2);
    return u;
}

static __device__ __forceinline__ void gld_lds16(const u16* gp, u16* lp) {
    __builtin_amdgcn_global_load_lds(
        (__attribute__((address_space(1))) void*)(u16*)gp,
        (__attribute__((address_space(3))) void*)lp, 16, 0, 0);
}

static __device__ __forceinline__ float ex2(float x) {
    float r; asm("v_exp_f32 %0, %1" : "=v"(r) : "v"(x)); return r;
}
static __device__ __forceinline__ float lg2(float x) {
    float r; asm("v_log_f32 %0, %1" : "=v"(r) : "v"(x)); return r;
}
static __device__ __forceinline__ float max3f(float a, float b, float c) {
    float r; asm("v_max3_f32 %0, %1, %2, %3" : "=v"(r) : "v"(a), "v"(b), "v"(c)); return r;
}

// ---------------- fp32 -> bf16 convert (8 elems/thread) ----------------
__global__ __launch_bounds__(256) void f32_to_bf16_k(const float* __restrict__ in,
                                                     u16* __restrict__ out) {
    int idx = blockIdx.x * 256 + threadIdx.x;
    fvec4 a = *((const fvec4*)in + idx * 2);
    fvec4 b = *((const fvec4*)in + idx * 2 + 1);
    ushort8 o;
#pragma unroll
    for (int e = 0; e < 4; ++e) { o[e] = f2bf(a[e]); o[4 + e] = f2bf(b[e]); }
    *((ushort8*)out + idx) = o;
}

// ---------------- row squared-norms * log2e ----------------
__global__ __launch_bounds__(256) void row_norms_k(const float* __restrict__ X,
                                                   float* __restrict__ out) {
    int wave = threadIdx.x >> 6;
    int lane = threadIdx.x & 63;
    int row  = blockIdx.x * 4 + wave;
    const float* xr = X + (size_t)row * D;
    float s = 0.f;
#pragma unroll
    for (int k = 0; k < D / 64; ++k) {
        float v = xr[lane + 64 * k];
        s += v * v;
    }
#pragma unroll
    for (int off = 32; off >= 1; off >>= 1) s += __shfl_down(s, off);
    if (lane == 0) out[row] = s * LOG2E;
}

// ---------------- dot-product matrix via bf16 MFMA (m97 pattern) -------
// DOT[i][j] = bf16(X_i . Y_j); also per-block max|dot| -> blockmax[]
__global__ __launch_bounds__(256) void gemm_dot_k(const u16* __restrict__ A,
                                                  const u16* __restrict__ B,
                                                  u16* __restrict__ DOT,
                                                  float* __restrict__ blockmax) {
    __shared__ u16 As[128 * 32];
    __shared__ u16 Bs[128 * 32];
    int tid = threadIdx.x;
    int wave = tid >> 6, lane = tid & 63;
    int i0 = blockIdx.y * 128, j0 = blockIdx.x * 128;
    int wr = (wave >> 1) * 64, wc = (wave & 1) * 64;

    fvec4 acc[4][4] = {};

    int srow = wave * 16 + (lane >> 2);
    int skk  = (lane & 3) * 8;
    const u16* ga0 = A + (size_t)(i0 + srow) * D + skk;
    const u16* ga1 = A + (size_t)(i0 + 64 + srow) * D + skk;
    const u16* gb0 = B + (size_t)(j0 + srow) * D + skk;
    const u16* gb1 = B + (size_t)(j0 + 64 + srow) * D + skk;
    u16* la0 = &As[(wave * 16) * 32];
    u16* la1 = &As[(64 + wave * 16) * 32];
    u16* lb0 = &Bs[(wave * 16) * 32];
    u16* lb1 = &Bs[(64 + wave * 16) * 32];

    int fr = lane & 15, q = lane >> 4;

    for (int k0 = 0; k0 < D; k0 += 32) {
        __syncthreads();
        gld_lds16(ga0 + k0, la0);
        gld_lds16(ga1 + k0, la1);
        gld_lds16(gb0 + k0, lb0);
        gld_lds16(gb1 + k0, lb1);
        __syncthreads();
        short8 af[4], bf[4];
#pragma unroll
        for (int t = 0; t < 4; ++t) {
            af[t] = *(const short8*)&As[(wr + t * 16 + fr) * 32 + q * 8];
            bf[t] = *(const short8*)&Bs[(wc + t * 16 + fr) * 32 + q * 8];
        }
#pragma unroll
        for (int ri = 0; ri < 4; ++ri)
#pragma unroll
            for (int ci = 0; ci < 4; ++ci)
                acc[ri][ci] = __builtin_amdgcn_mfma_f32_16x16x32_bf16(af[ri], bf[ci],
                                                                      acc[ri][ci], 0, 0, 0);
    }

    float lmax = 0.f;
#pragma unroll
    for (int ri = 0; ri < 4; ++ri) {
#pragma unroll
        for (int ci = 0; ci < 4; ++ci) {
            int j = j0 + wc + ci * 16 + fr;
#pragma unroll
            for (int r = 0; r < 4; ++r) {
                int i = i0 + wr + ri * 16 + q * 4 + r;
                float dv = acc[ri][ci][r];
                DOT[(size_t)i * N + j] = f2bf(dv);
                lmax = fmaxf(lmax, fabsf(dv));
            }
        }
    }
#pragma unroll
    for (int off = 32; off >= 1; off >>= 1) lmax = fmaxf(lmax, __shfl_xor(lmax, off));
    __shared__ float bm[4];
    if (lane == 0) bm[wave] = lmax;
    __syncthreads();
    if (tid == 0)
        blockmax[blockIdx.y * gridDim.x + blockIdx.x] =
            fmaxf(fmaxf(bm[0], bm[1]), fmaxf(bm[2], bm[3]));
}

// ---------------- consts: qs, invS, C from max|dot| ----------------
__global__ __launch_bounds__(256) void setup_consts_k(const float* __restrict__ blockmax,
                                                      float* __restrict__ consts) {
    int t = threadIdx.x;
    float m = fmaxf(fmaxf(blockmax[t], blockmax[t + 256]),
                    fmaxf(blockmax[t + 512], blockmax[t + 768]));
#pragma unroll
    for (int off = 32; off >= 1; off >>= 1) m = fmaxf(m, __shfl_xor(m, off));
    __shared__ float bm[4];
    if ((t & 63) == 0) bm[t >> 6] = m;
    __syncthreads();
    if (t == 0) {
        float maxd = fmaxf(fmaxf(bm[0], bm[1]), fmaxf(bm[2], bm[3]));
        maxd = fmaxf(maxd, 1e-6f);
        consts[0] = 127.0f / maxd;                    // qs (quant scale on dot)
        float invS = 2.0f * LOG2E * maxd / 127.0f;    // dequant step (log2 units)
        consts[1] = invS;
        consts[2] = 127.5f * invS;                    // C
    }
}

// ---------------- quantize DOT -> Q (u8), row-major ----------------
__global__ __launch_bounds__(256) void quant_k(const u16* __restrict__ DOT,
                                               const float* __restrict__ consts,
                                               u8* __restrict__ Q) {
    int idx = blockIdx.x * 256 + threadIdx.x;
    float qs = consts[0];
    ushort8 dv = *((const ushort8*)DOT + idx);
    unsigned o0 = 0, o1 = 0;
#pragma unroll
    for (int e = 0; e < 8; ++e) {
        float r = fmaf(bf2f(dv[e]), -qs, 127.5f);
        r = fminf(fmaxf(r, 0.f), 255.f);
        unsigned qq = (unsigned)(int)(r + 0.5f);
        if (e < 4) o0 |= qq << (8 * e); else o1 |= qq << (8 * (e - 4));
    }
    uivec2 o; o[0] = o0; o[1] = o1;
    *((uivec2*)Q + idx) = o;
}

// ---------------- transposing quantize: DOT -> QT (u8) ----------------
__global__ __launch_bounds__(256) void quantT_k(const u16* __restrict__ DOT,
                                                const float* __restrict__ consts,
                                                u8* __restrict__ QT) {
    __shared__ u16 tile[64][66];
    int bx = blockIdx.x * 64, by = blockIdx.y * 64;
    int t = threadIdx.x;
    int tx = t & 63, ty = t >> 6;
#pragma unroll
    for (int r = 0; r < 64; r += 4)
        tile[r + ty][tx] = DOT[(size_t)(by + r + ty) * N + bx + tx];
    __syncthreads();
    float qs = consts[0];
    int ro = t >> 2, co0 = (t & 3) << 4;
    unsigned w[4] = {0, 0, 0, 0};
#pragma unroll
    for (int k = 0; k < 16; ++k) {
        float v = bf2f(tile[co0 + k][ro]);
        float r = fminf(fmaxf(fmaf(v, -qs, 127.5f), 0.f), 255.f);
        unsigned qq = (unsigned)(int)(r + 0.5f);
        w[k >> 2] |= qq << ((k & 3) * 8);
    }
    uivec4 o; o[0] = w[0]; o[1] = w[1]; o[2] = w[2]; o[3] = w[3];
    *(uivec4*)&QT[(size_t)(bx + ro) * N + by + co0] = o;
}

// ---------------- Wg init: g=0 -> Wg = -y2c ----------------
__global__ __launch_bounds__(256) void init_wg_k(const float* __restrict__ y2c,
                                                 float* __restrict__ Wg) {
    int i = blockIdx.x * 256 + threadIdx.x;
    Wg[i] = -y2c[i];
}

// ---------------- Sinkhorn half-step on u8 Q, with fixpoint early-exit ----
// tv''_j = Win_j - q_ij*invS ; base = LA2 - C - LSE''(row)
// wout = base (next half's Win), vout = base + normR.
// chg protocol: if the two previous halves changed nothing (bitwise), the
// iteration is at its fp32 fixed point -> identity forever -> exit.
__global__ __launch_bounds__(256, 4) void sinkhorn_half_q_k(const u8* __restrict__ Q,
                                                            const float* __restrict__ Win,
                                                            const float* __restrict__ normR,
                                                            const float* __restrict__ consts,
                                                            float* __restrict__ vout,
                                                            float* __restrict__ wout,
                                                            int* __restrict__ chg,
                                                            int d) {
    if (chg[d - 1] == 0 && chg[d - 2] == 0) return;  // uniform: fixpoint reached
    __shared__ int blkchg;
    if (threadIdx.x == 0) blkchg = 0;
    int wid  = (blockIdx.x << 2) | (threadIdx.x >> 6);  // row 0..4095
    int lane = threadIdx.x & 63;
    float invS = consts[1], C = consts[2];
    float oldw = wout[wid];
    const u8* row = Q + ((size_t)wid << 12);
    float m = -1e30f, s = 0.f;
#pragma unroll
    for (int c = 0; c < 8; ++c) {
        int j = c * 512 + lane * 8;
        uivec2 qv = *(const uivec2*)(row + j);
        fvec4 w0 = *(const fvec4*)(Win + j);
        fvec4 w1 = *(const fvec4*)(Win + j + 4);
        float tv[8];
#pragma unroll
        for (int e = 0; e < 4; ++e) {
            tv[e]     = fmaf(-invS, (float)((qv[0] >> (8 * e)) & 255u), w0[e]);
            tv[4 + e] = fmaf(-invS, (float)((qv[1] >> (8 * e)) & 255u), w1[e]);
        }
        float mh = fmaxf(fmaxf(max3f(tv[0], tv[1], tv[2]), max3f(tv[3], tv[4], tv[5])),
                         max3f(tv[6], tv[7], m));
        float sh = 0.f;
#pragma unroll
        for (int e = 0; e < 8; ++e) sh += ex2(tv[e] - mh);
        s = fmaf(s, ex2(m - mh), sh);
        m = mh;
    }
    __syncthreads();  // blkchg=0 visible
#pragma unroll
    for (int off = 32; off >= 1; off >>= 1) {
        float mo = __shfl_xor(m, off);
        float so = __shfl_xor(s, off);
        float mn = fmaxf(m, mo);
        s = fmaf(s, ex2(m - mn), so * ex2(mo - mn));
        m = mn;
    }
    if (lane == 0) {
        float base = LA2 - C - (m + lg2(s));
        wout[wid] = base;
        vout[wid] = base + normR[wid];
        if (__float_as_uint(base) != __float_as_uint(oldw)) blkchg = 1;
    }
    __syncthreads();
    if (threadIdx.x == 0 && blkchg) chg[d] = 1;  // plain store; races benign
}

// ---------------- objective partials on u8 Q ----------------
// p = exp2(Wf_i + C + Wg_j - q*invS); weight = ln2*(f2_i+g2_j) + VADD
__global__ __launch_bounds__(256, 4) void ot_value_q_k(const u8* __restrict__ Q,
                                                       const float* __restrict__ Wg,
                                                       const float* __restrict__ g2,
                                                       const float* __restrict__ f2,
                                                       const float* __restrict__ Wf,
                                                       const float* __restrict__ consts,
                                                       float* __restrict__ partial) {
    int wid  = (blockIdx.x << 2) | (threadIdx.x >> 6);
    int lane = threadIdx.x & 63;
    float invS = consts[1], C = consts[2];
    const u8* row = Q + ((size_t)wid << 12);
    float fi = f2[wid];
    float eWF = Wf[wid] + C;
    float wrow = fmaf(LN2, fi, VADD);
    float local = 0.f;
#pragma unroll
    for (int c = 0; c < 8; ++c) {
        int j = c * 512 + lane * 8;
        uivec2 qv = *(const uivec2*)(row + j);
        fvec4 wg0 = *(const fvec4*)(Wg + j);
        fvec4 wg1 = *(const fvec4*)(Wg + j + 4);
        fvec4 g0 = *(const fvec4*)(g2 + j);
        fvec4 g1 = *(const fvec4*)(g2 + j + 4);
#pragma unroll
        for (int e = 0; e < 4; ++e) {
            float p0 = ex2(fmaf(-invS, (float)((qv[0] >> (8 * e)) & 255u), wg0[e]) + eWF);
            float p1 = ex2(fmaf(-invS, (float)((qv[1] >> (8 * e)) & 255u), wg1[e]) + eWF);
            local = fmaf(p0, fmaf(LN2, g0[e], wrow), local);
            local = fmaf(p1, fmaf(LN2, g1[e], wrow), local);
        }
    }
#pragma unroll
    for (int off = 32; off >= 1; off >>= 1) local += __shfl_xor(local, off);
    __shared__ float ps[4];
    if (lane == 0) ps[threadIdx.x >> 6] = local;
    __syncthreads();
    if (threadIdx.x == 0) partial[blockIdx.x] = ps[0] + ps[1] + ps[2] + ps[3];
}

__global__ __launch_bounds__(256) void value_reduce_k(const float* __restrict__ partial,
                                                      float* __restrict__ out) {
    int t = threadIdx.x;
    float s = partial[t] + partial[t + 256] + partial[t + 512] + partial[t + 768];
#pragma unroll
    for (int off = 32; off >= 1; off >>= 1) s += __shfl_xor(s, off);
    __shared__ float fs[4];
    if ((t & 63) == 0) fs[t >> 6] = s;
    __syncthreads();
    if (t == 0) out[0] = fs[0] + fs[1] + fs[2] + fs[3] + 1.0f;
}

extern "C" void kernel_launch(void* const* d_in, const int* in_sizes, int n_in,
                              void* d_out, int out_size, void* d_ws, size_t ws_size,
                              hipStream_t stream) {
    const float* src = (const float*)d_in[0];
    const float* tgt = (const float*)d_in[1];
    float* out = (float*)d_out;

    // workspace: DOT bf16 (32MB) | Qb u8 (16MB) | QTb u8 (16MB) | vectors (~132KB)
    // Xb/Yb (GEMM inputs) alias the QTb region: dead before quantT_k writes QT.
    char* ws = (char*)d_ws;
    u16* DOT = (u16*)ws;
    u8*  Qb  = (u8*)(ws + (32u << 20));
    u8*  QTb = (u8*)(ws + (48u << 20));
    u16* Xb  = (u16*)(ws + (48u << 20));
    u16* Yb  = (u16*)(ws + (52u << 20));
    float* x2c = (float*)(ws + (64u << 20));
    float* y2c = x2c + N;
    float* f   = y2c + N;
    float* g   = f + N;
    float* Wf  = g + N;
    float* Wg  = Wf + N;
    float* blockmax = Wg + N;          // 1024 floats
    float* consts   = blockmax + 1024;
    float* partial  = consts + 16;     // 1024 floats
    int*   chgbase  = (int*)(partial + 1024);  // [2 sentinels][200 slots]
    int*   chg      = chgbase + 2;

    f32_to_bf16_k<<<N * D / (256 * 8), 256, 0, stream>>>(src, Xb);
    f32_to_bf16_k<<<N * D / (256 * 8), 256, 0, stream>>>(tgt, Yb);
    row_norms_k<<<N / 4, 256, 0, stream>>>(src, x2c);
    row_norms_k<<<N / 4, 256, 0, stream>>>(tgt, y2c);
    gemm_dot_k<<<dim3(N / 128, N / 128), 256, 0, stream>>>(Xb, Yb, DOT, blockmax);
    setup_consts_k<<<1, 256, 0, stream>>>(blockmax, consts);
    quant_k<<<N * N / (256 * 8), 256, 0, stream>>>(DOT, consts, Qb);
    quantT_k<<<dim3(N / 64, N / 64), 256, 0, stream>>>(DOT, consts, QTb);
    init_wg_k<<<N / 256, 256, 0, stream>>>(y2c, Wg);

    hipMemsetAsync(chgbase, 0xFF, 2 * sizeof(int), stream);   // sentinels != 0
    hipMemsetAsync(chg, 0, 200 * sizeof(int), stream);        // change flags

    for (int it = 0; it < 100; ++it) {
        sinkhorn_half_q_k<<<N / 4, 256, 0, stream>>>(Qb,  Wg, x2c, consts, f, Wf,
                                                     chg, 2 * it);
        sinkhorn_half_q_k<<<N / 4, 256, 0, stream>>>(QTb, Wf, y2c, consts, g, Wg,
                                                     chg, 2 * it + 1);
    }

    ot_value_q_k<<<N / 4, 256, 0, stream>>>(Qb, Wg, g, f, Wf, consts, partial);
    value_reduce_k<<<1, 256, 0, stream>>>(partial, out);
}

// Round 7
// 1360.097 us; speedup vs baseline: 1.0545x; 1.0545x over previous
//
#include <hip/hip_runtime.h>
#include <hip/hip_bf16.h>

#define N 4096
#define D 512
#define LOG2E 1.4426950408889634f
#define LN2   0.6931471805599453f
#define LA2   (-12.0f)                 // -log2(4096)
#define VADD  15.635532333438686f      // -(la + lb + 1)

typedef unsigned short u16;
typedef unsigned char u8;
typedef __attribute__((ext_vector_type(8))) short short8;
typedef __attribute__((ext_vector_type(8))) unsigned short ushort8;
typedef __attribute__((ext_vector_type(4))) float fvec4;
typedef __attribute__((ext_vector_type(2))) unsigned int uivec2;
typedef __attribute__((ext_vector_type(4))) unsigned int uivec4;

static __device__ __forceinline__ float bf2f(unsigned short u) {
    union { unsigned int i; float f; } c;
    c.i = ((unsigned int)u) << 16;
    return c.f;
}

static __device__ __forceinline__ unsigned short f2bf(float x) {
    __hip_bfloat16 h = __float2bfloat16(x);  // RNE
    unsigned short u;
    __builtin_memcpy(&u, &h, 2);
    return u;
}

static __device__ __forceinline__ void gld_lds16(const u16* gp, u16* lp) {
    __builtin_amdgcn_global_load_lds(
        (__attribute__((address_space(1))) void*)(u16*)gp,
        (__attribute__((address_space(3))) void*)lp, 16, 0, 0);
}

static __device__ __forceinline__ float ex2(float x) {
    float r; asm("v_exp_f32 %0, %1" : "=v"(r) : "v"(x)); return r;
}
static __device__ __forceinline__ float lg2(float x) {
    float r; asm("v_log_f32 %0, %1" : "=v"(r) : "v"(x)); return r;
}
static __device__ __forceinline__ float max3f(float a, float b, float c) {
    float r; asm("v_max3_f32 %0, %1, %2, %3" : "=v"(r) : "v"(a), "v"(b), "v"(c)); return r;
}

// ---------------- fp32 -> bf16 convert (8 elems/thread) ----------------
__global__ __launch_bounds__(256) void f32_to_bf16_k(const float* __restrict__ in,
                                                     u16* __restrict__ out) {
    int idx = blockIdx.x * 256 + threadIdx.x;
    fvec4 a = *((const fvec4*)in + idx * 2);
    fvec4 b = *((const fvec4*)in + idx * 2 + 1);
    ushort8 o;
#pragma unroll
    for (int e = 0; e < 4; ++e) { o[e] = f2bf(a[e]); o[4 + e] = f2bf(b[e]); }
    *((ushort8*)out + idx) = o;
}

// ---------------- row squared-norms * log2e ----------------
__global__ __launch_bounds__(256) void row_norms_k(const float* __restrict__ X,
                                                   float* __restrict__ out) {
    int wave = threadIdx.x >> 6;
    int lane = threadIdx.x & 63;
    int row  = blockIdx.x * 4 + wave;
    const float* xr = X + (size_t)row * D;
    float s = 0.f;
#pragma unroll
    for (int k = 0; k < D / 64; ++k) {
        float v = xr[lane + 64 * k];
        s += v * v;
    }
#pragma unroll
    for (int off = 32; off >= 1; off >>= 1) s += __shfl_down(s, off);
    if (lane == 0) out[row] = s * LOG2E;
}

// ---------------- dot-product matrix via bf16 MFMA (m97 pattern) -------
// DOT[i][j] = bf16(X_i . Y_j); also per-block max|dot| -> blockmax[]
__global__ __launch_bounds__(256) void gemm_dot_k(const u16* __restrict__ A,
                                                  const u16* __restrict__ B,
                                                  u16* __restrict__ DOT,
                                                  float* __restrict__ blockmax) {
    __shared__ u16 As[128 * 32];
    __shared__ u16 Bs[128 * 32];
    int tid = threadIdx.x;
    int wave = tid >> 6, lane = tid & 63;
    int i0 = blockIdx.y * 128, j0 = blockIdx.x * 128;
    int wr = (wave >> 1) * 64, wc = (wave & 1) * 64;

    fvec4 acc[4][4] = {};

    int srow = wave * 16 + (lane >> 2);
    int skk  = (lane & 3) * 8;
    const u16* ga0 = A + (size_t)(i0 + srow) * D + skk;
    const u16* ga1 = A + (size_t)(i0 + 64 + srow) * D + skk;
    const u16* gb0 = B + (size_t)(j0 + srow) * D + skk;
    const u16* gb1 = B + (size_t)(j0 + 64 + srow) * D + skk;
    u16* la0 = &As[(wave * 16) * 32];
    u16* la1 = &As[(64 + wave * 16) * 32];
    u16* lb0 = &Bs[(wave * 16) * 32];
    u16* lb1 = &Bs[(64 + wave * 16) * 32];

    int fr = lane & 15, q = lane >> 4;

    for (int k0 = 0; k0 < D; k0 += 32) {
        __syncthreads();
        gld_lds16(ga0 + k0, la0);
        gld_lds16(ga1 + k0, la1);
        gld_lds16(gb0 + k0, lb0);
        gld_lds16(gb1 + k0, lb1);
        __syncthreads();
        short8 af[4], bf[4];
#pragma unroll
        for (int t = 0; t < 4; ++t) {
            af[t] = *(const short8*)&As[(wr + t * 16 + fr) * 32 + q * 8];
            bf[t] = *(const short8*)&Bs[(wc + t * 16 + fr) * 32 + q * 8];
        }
#pragma unroll
        for (int ri = 0; ri < 4; ++ri)
#pragma unroll
            for (int ci = 0; ci < 4; ++ci)
                acc[ri][ci] = __builtin_amdgcn_mfma_f32_16x16x32_bf16(af[ri], bf[ci],
                                                                      acc[ri][ci], 0, 0, 0);
    }

    float lmax = 0.f;
#pragma unroll
    for (int ri = 0; ri < 4; ++ri) {
#pragma unroll
        for (int ci = 0; ci < 4; ++ci) {
            int j = j0 + wc + ci * 16 + fr;
#pragma unroll
            for (int r = 0; r < 4; ++r) {
                int i = i0 + wr + ri * 16 + q * 4 + r;
                float dv = acc[ri][ci][r];
                DOT[(size_t)i * N + j] = f2bf(dv);
                lmax = fmaxf(lmax, fabsf(dv));
            }
        }
    }
#pragma unroll
    for (int off = 32; off >= 1; off >>= 1) lmax = fmaxf(lmax, __shfl_xor(lmax, off));
    __shared__ float bm[4];
    if (lane == 0) bm[wave] = lmax;
    __syncthreads();
    if (tid == 0)
        blockmax[blockIdx.y * gridDim.x + blockIdx.x] =
            fmaxf(fmaxf(bm[0], bm[1]), fmaxf(bm[2], bm[3]));
}

// ---------------- consts: qs, invS, C from max|dot| ----------------
__global__ __launch_bounds__(256) void setup_consts_k(const float* __restrict__ blockmax,
                                                      float* __restrict__ consts) {
    int t = threadIdx.x;
    float m = fmaxf(fmaxf(blockmax[t], blockmax[t + 256]),
                    fmaxf(blockmax[t + 512], blockmax[t + 768]));
#pragma unroll
    for (int off = 32; off >= 1; off >>= 1) m = fmaxf(m, __shfl_xor(m, off));
    __shared__ float bm[4];
    if ((t & 63) == 0) bm[t >> 6] = m;
    __syncthreads();
    if (t == 0) {
        float maxd = fmaxf(fmaxf(bm[0], bm[1]), fmaxf(bm[2], bm[3]));
        maxd = fmaxf(maxd, 1e-6f);
        consts[0] = 127.0f / maxd;                    // qs (quant scale on dot)
        float invS = 2.0f * LOG2E * maxd / 127.0f;    // dequant step (log2 units)
        consts[1] = invS;
        consts[2] = 127.5f * invS;                    // C
    }
}

// ---------------- quantize DOT -> Q (u8), row-major ----------------
__global__ __launch_bounds__(256) void quant_k(const u16* __restrict__ DOT,
                                               const float* __restrict__ consts,
                                               u8* __restrict__ Q) {
    int idx = blockIdx.x * 256 + threadIdx.x;
    float qs = consts[0];
    ushort8 dv = *((const ushort8*)DOT + idx);
    unsigned o0 = 0, o1 = 0;
#pragma unroll
    for (int e = 0; e < 8; ++e) {
        float r = fmaf(bf2f(dv[e]), -qs, 127.5f);
        r = fminf(fmaxf(r, 0.f), 255.f);
        unsigned qq = (unsigned)(int)(r + 0.5f);
        if (e < 4) o0 |= qq << (8 * e); else o1 |= qq << (8 * (e - 4));
    }
    uivec2 o; o[0] = o0; o[1] = o1;
    *((uivec2*)Q + idx) = o;
}

// ---------------- transposing quantize: DOT -> QT (u8) ----------------
__global__ __launch_bounds__(256) void quantT_k(const u16* __restrict__ DOT,
                                                const float* __restrict__ consts,
                                                u8* __restrict__ QT) {
    __shared__ u16 tile[64][66];
    int bx = blockIdx.x * 64, by = blockIdx.y * 64;
    int t = threadIdx.x;
    int tx = t & 63, ty = t >> 6;
#pragma unroll
    for (int r = 0; r < 64; r += 4)
        tile[r + ty][tx] = DOT[(size_t)(by + r + ty) * N + bx + tx];
    __syncthreads();
    float qs = consts[0];
    int ro = t >> 2, co0 = (t & 3) << 4;
    unsigned w[4] = {0, 0, 0, 0};
#pragma unroll
    for (int k = 0; k < 16; ++k) {
        float v = bf2f(tile[co0 + k][ro]);
        float r = fminf(fmaxf(fmaf(v, -qs, 127.5f), 0.f), 255.f);
        unsigned qq = (unsigned)(int)(r + 0.5f);
        w[k >> 2] |= qq << ((k & 3) * 8);
    }
    uivec4 o; o[0] = w[0]; o[1] = w[1]; o[2] = w[2]; o[3] = w[3];
    *(uivec4*)&QT[(size_t)(bx + ro) * N + by + co0] = o;
}

// ---------------- Wg init: g=0 -> Wg = -y2c ----------------
__global__ __launch_bounds__(256) void init_wg_k(const float* __restrict__ y2c,
                                                 float* __restrict__ Wg) {
    int i = blockIdx.x * 256 + threadIdx.x;
    Wg[i] = -y2c[i];
}

// ---------------- Sinkhorn half-step on u8 Q: 2 waves per row ----------
// Grid 2048 x 256 (__launch_bounds__(256,8)) -> 8 blocks/CU = 100% occupancy.
// Wave pair (2w, 2w+1) handles row (blockIdx*2 + w): each wave covers 2048
// columns (32 elems/lane, 4 chunks), LDS merge combines the two (m,s).
// tv_j = Win_j - q_ij*invS ; base = LA2 - C - LSE(row)
// wout = base (next half's Win), vout = base + normR.
__global__ __launch_bounds__(256, 8) void sinkhorn_half_q_k(const u8* __restrict__ Q,
                                                            const float* __restrict__ Win,
                                                            const float* __restrict__ normR,
                                                            const float* __restrict__ consts,
                                                            float* __restrict__ vout,
                                                            float* __restrict__ wout) {
    int wave = threadIdx.x >> 6;
    int lane = threadIdx.x & 63;
    int row  = (blockIdx.x << 1) | (wave >> 1);      // row 0..4095
    int colb = (wave & 1) << 11;                     // 0 or 2048
    float invS = consts[1], C = consts[2];
    const u8* rp = Q + ((size_t)row << 12) + colb;
    const float* wp = Win + colb;
    float m = -1e30f, s = 0.f;
#pragma unroll
    for (int c = 0; c < 4; ++c) {
        int j = c * 512 + lane * 8;
        uivec2 qv = *(const uivec2*)(rp + j);
        fvec4 w0 = *(const fvec4*)(wp + j);
        fvec4 w1 = *(const fvec4*)(wp + j + 4);
        float tv[8];
#pragma unroll
        for (int e = 0; e < 4; ++e) {
            tv[e]     = fmaf(-invS, (float)((qv[0] >> (8 * e)) & 255u), w0[e]);
            tv[4 + e] = fmaf(-invS, (float)((qv[1] >> (8 * e)) & 255u), w1[e]);
        }
        float mh = fmaxf(fmaxf(max3f(tv[0], tv[1], tv[2]), max3f(tv[3], tv[4], tv[5])),
                         max3f(tv[6], tv[7], m));
        float sh = 0.f;
#pragma unroll
        for (int e = 0; e < 8; ++e) sh += ex2(tv[e] - mh);
        s = fmaf(s, ex2(m - mh), sh);
        m = mh;
    }
#pragma unroll
    for (int off = 32; off >= 1; off >>= 1) {
        float mo = __shfl_xor(m, off);
        float so = __shfl_xor(s, off);
        float mn = fmaxf(m, mo);
        s = fmaf(s, ex2(m - mn), so * ex2(mo - mn));
        m = mn;
    }
    __shared__ float sm[4], ss[4];
    if (lane == 0) { sm[wave] = m; ss[wave] = s; }
    __syncthreads();
    if (lane == 0 && (wave & 1) == 0) {
        float m0 = sm[wave], m1 = sm[wave + 1];
        float mn = fmaxf(m0, m1);
        float sv = fmaf(ss[wave], ex2(m0 - mn), ss[wave + 1] * ex2(m1 - mn));
        float base = LA2 - C - (mn + lg2(sv));
        wout[row] = base;
        vout[row] = base + normR[row];
    }
}

// ---------------- objective partials on u8 Q ----------------
// p = exp2(Wf_i + C + Wg_j - q*invS); weight = ln2*(f2_i+g2_j) + VADD
__global__ __launch_bounds__(256, 4) void ot_value_q_k(const u8* __restrict__ Q,
                                                       const float* __restrict__ Wg,
                                                       const float* __restrict__ g2,
                                                       const float* __restrict__ f2,
                                                       const float* __restrict__ Wf,
                                                       const float* __restrict__ consts,
                                                       float* __restrict__ partial) {
    int wid  = (blockIdx.x << 2) | (threadIdx.x >> 6);
    int lane = threadIdx.x & 63;
    float invS = consts[1], C = consts[2];
    const u8* row = Q + ((size_t)wid << 12);
    float fi = f2[wid];
    float eWF = Wf[wid] + C;
    float wrow = fmaf(LN2, fi, VADD);
    float local = 0.f;
#pragma unroll
    for (int c = 0; c < 8; ++c) {
        int j = c * 512 + lane * 8;
        uivec2 qv = *(const uivec2*)(row + j);
        fvec4 wg0 = *(const fvec4*)(Wg + j);
        fvec4 wg1 = *(const fvec4*)(Wg + j + 4);
        fvec4 g0 = *(const fvec4*)(g2 + j);
        fvec4 g1 = *(const fvec4*)(g2 + j + 4);
#pragma unroll
        for (int e = 0; e < 4; ++e) {
            float p0 = ex2(fmaf(-invS, (float)((qv[0] >> (8 * e)) & 255u), wg0[e]) + eWF);
            float p1 = ex2(fmaf(-invS, (float)((qv[1] >> (8 * e)) & 255u), wg1[e]) + eWF);
            local = fmaf(p0, fmaf(LN2, g0[e], wrow), local);
            local = fmaf(p1, fmaf(LN2, g1[e], wrow), local);
        }
    }
#pragma unroll
    for (int off = 32; off >= 1; off >>= 1) local += __shfl_xor(local, off);
    __shared__ float ps[4];
    if (lane == 0) ps[threadIdx.x >> 6] = local;
    __syncthreads();
    if (threadIdx.x == 0) partial[blockIdx.x] = ps[0] + ps[1] + ps[2] + ps[3];
}

__global__ __launch_bounds__(256) void value_reduce_k(const float* __restrict__ partial,
                                                      float* __restrict__ out) {
    int t = threadIdx.x;
    float s = partial[t] + partial[t + 256] + partial[t + 512] + partial[t + 768];
#pragma unroll
    for (int off = 32; off >= 1; off >>= 1) s += __shfl_xor(s, off);
    __shared__ float fs[4];
    if ((t & 63) == 0) fs[t >> 6] = s;
    __syncthreads();
    if (t == 0) out[0] = fs[0] + fs[1] + fs[2] + fs[3] + 1.0f;
}

extern "C" void kernel_launch(void* const* d_in, const int* in_sizes, int n_in,
                              void* d_out, int out_size, void* d_ws, size_t ws_size,
                              hipStream_t stream) {
    const float* src = (const float*)d_in[0];
    const float* tgt = (const float*)d_in[1];
    float* out = (float*)d_out;

    // workspace: DOT bf16 (32MB) | Qb u8 (16MB) | QTb u8 (16MB) | vectors (~132KB)
    // Xb/Yb (GEMM inputs) alias the QTb region: dead before quantT_k writes QT.
    char* ws = (char*)d_ws;
    u16* DOT = (u16*)ws;
    u8*  Qb  = (u8*)(ws + (32u << 20));
    u8*  QTb = (u8*)(ws + (48u << 20));
    u16* Xb  = (u16*)(ws + (48u << 20));
    u16* Yb  = (u16*)(ws + (52u << 20));
    float* x2c = (float*)(ws + (64u << 20));
    float* y2c = x2c + N;
    float* f   = y2c + N;
    float* g   = f + N;
    float* Wf  = g + N;
    float* Wg  = Wf + N;
    float* blockmax = Wg + N;          // 1024 floats
    float* consts   = blockmax + 1024;
    float* partial  = consts + 16;     // 1024 floats

    f32_to_bf16_k<<<N * D / (256 * 8), 256, 0, stream>>>(src, Xb);
    f32_to_bf16_k<<<N * D / (256 * 8), 256, 0, stream>>>(tgt, Yb);
    row_norms_k<<<N / 4, 256, 0, stream>>>(src, x2c);
    row_norms_k<<<N / 4, 256, 0, stream>>>(tgt, y2c);
    gemm_dot_k<<<dim3(N / 128, N / 128), 256, 0, stream>>>(Xb, Yb, DOT, blockmax);
    setup_consts_k<<<1, 256, 0, stream>>>(blockmax, consts);
    quant_k<<<N * N / (256 * 8), 256, 0, stream>>>(DOT, consts, Qb);
    quantT_k<<<dim3(N / 64, N / 64), 256, 0, stream>>>(DOT, consts, QTb);
    init_wg_k<<<N / 256, 256, 0, stream>>>(y2c, Wg);

    for (int it = 0; it < 100; ++it) {
        sinkhorn_half_q_k<<<N / 2, 256, 0, stream>>>(Qb,  Wg, x2c, consts, f, Wf);
        sinkhorn_half_q_k<<<N / 2, 256, 0, stream>>>(QTb, Wf, y2c, consts, g, Wg);
    }

    ot_value_q_k<<<N / 4, 256, 0, stream>>>(Qb, Wg, g, f, Wf, consts, partial);
    value_reduce_k<<<1, 256, 0, stream>>>(partial, out);
}

// Round 9
// 1297.473 us; speedup vs baseline: 1.1054x; 1.0483x over previous
//
#include <hip/hip_runtime.h>
#include <hip/hip_bf16.h>

#define N 4096
#define D 512
#define LOG2E 1.4426950408889634f
#define LN2   0.6931471805599453f
#define LA2   (-12.0f)                 // -log2(4096)
#define VADD  15.635532333438686f      // -(la + lb + 1)

typedef unsigned short u16;
typedef unsigned char u8;
typedef __attribute__((ext_vector_type(8))) short short8;
typedef __attribute__((ext_vector_type(8))) unsigned short ushort8;
typedef __attribute__((ext_vector_type(4))) float fvec4;
typedef __attribute__((ext_vector_type(2))) unsigned int uivec2;
typedef __attribute__((ext_vector_type(4))) unsigned int uivec4;

static __device__ __forceinline__ float bf2f(unsigned short u) {
    union { unsigned int i; float f; } c;
    c.i = ((unsigned int)u) << 16;
    return c.f;
}

static __device__ __forceinline__ unsigned short f2bf(float x) {
    __hip_bfloat16 h = __float2bfloat16(x);  // RNE
    unsigned short u;
    __builtin_memcpy(&u, &h, 2);
    return u;
}

static __device__ __forceinline__ void gld_lds16(const u16* gp, u16* lp) {
    __builtin_amdgcn_global_load_lds(
        (__attribute__((address_space(1))) void*)(u16*)gp,
        (__attribute__((address_space(3))) void*)lp, 16, 0, 0);
}

static __device__ __forceinline__ float ex2(float x) {
    float r; asm("v_exp_f32 %0, %1" : "=v"(r) : "v"(x)); return r;
}
static __device__ __forceinline__ float lg2(float x) {
    float r; asm("v_log_f32 %0, %1" : "=v"(r) : "v"(x)); return r;
}
static __device__ __forceinline__ float max3f(float a, float b, float c) {
    float r; asm("v_max3_f32 %0, %1, %2, %3" : "=v"(r) : "v"(a), "v"(b), "v"(c)); return r;
}

// -------- fused fp32->bf16 convert + row squared-norms (*log2e) --------
// One wave per row: lane loads 8 floats, converts+stores bf16x8, norm-reduce.
__global__ __launch_bounds__(256) void xy_prep_k(const float* __restrict__ in,
                                                 u16* __restrict__ outb,
                                                 float* __restrict__ norms) {
    int wave = threadIdx.x >> 6, lane = threadIdx.x & 63;
    int row = blockIdx.x * 4 + wave;
    const float* xr = in + (size_t)row * D;
    fvec4 a = *(const fvec4*)(xr + lane * 8);
    fvec4 b = *(const fvec4*)(xr + lane * 8 + 4);
    float s = 0.f;
    ushort8 o;
#pragma unroll
    for (int e = 0; e < 4; ++e) {
        o[e] = f2bf(a[e]); o[4 + e] = f2bf(b[e]);
        s += a[e] * a[e] + b[e] * b[e];
    }
    *((ushort8*)(outb + (size_t)row * D) + lane) = o;
#pragma unroll
    for (int off = 32; off >= 1; off >>= 1) s += __shfl_down(s, off);
    if (lane == 0) norms[row] = s * LOG2E;
}

// ---------------- dot-product matrix via bf16 MFMA (m97 pattern) -------
// DOT[i][j] = bf16(X_i . Y_j); also per-block max|dot| -> blockmax[]
__global__ __launch_bounds__(256) void gemm_dot_k(const u16* __restrict__ A,
                                                  const u16* __restrict__ B,
                                                  u16* __restrict__ DOT,
                                                  float* __restrict__ blockmax) {
    __shared__ u16 As[128 * 32];
    __shared__ u16 Bs[128 * 32];
    int tid = threadIdx.x;
    int wave = tid >> 6, lane = tid & 63;
    int i0 = blockIdx.y * 128, j0 = blockIdx.x * 128;
    int wr = (wave >> 1) * 64, wc = (wave & 1) * 64;

    fvec4 acc[4][4] = {};

    int srow = wave * 16 + (lane >> 2);
    int skk  = (lane & 3) * 8;
    const u16* ga0 = A + (size_t)(i0 + srow) * D + skk;
    const u16* ga1 = A + (size_t)(i0 + 64 + srow) * D + skk;
    const u16* gb0 = B + (size_t)(j0 + srow) * D + skk;
    const u16* gb1 = B + (size_t)(j0 + 64 + srow) * D + skk;
    u16* la0 = &As[(wave * 16) * 32];
    u16* la1 = &As[(64 + wave * 16) * 32];
    u16* lb0 = &Bs[(wave * 16) * 32];
    u16* lb1 = &Bs[(64 + wave * 16) * 32];

    int fr = lane & 15, q = lane >> 4;

    for (int k0 = 0; k0 < D; k0 += 32) {
        __syncthreads();
        gld_lds16(ga0 + k0, la0);
        gld_lds16(ga1 + k0, la1);
        gld_lds16(gb0 + k0, lb0);
        gld_lds16(gb1 + k0, lb1);
        __syncthreads();
        short8 af[4], bf[4];
#pragma unroll
        for (int t = 0; t < 4; ++t) {
            af[t] = *(const short8*)&As[(wr + t * 16 + fr) * 32 + q * 8];
            bf[t] = *(const short8*)&Bs[(wc + t * 16 + fr) * 32 + q * 8];
        }
#pragma unroll
        for (int ri = 0; ri < 4; ++ri)
#pragma unroll
            for (int ci = 0; ci < 4; ++ci)
                acc[ri][ci] = __builtin_amdgcn_mfma_f32_16x16x32_bf16(af[ri], bf[ci],
                                                                      acc[ri][ci], 0, 0, 0);
    }

    float lmax = 0.f;
#pragma unroll
    for (int ri = 0; ri < 4; ++ri) {
#pragma unroll
        for (int ci = 0; ci < 4; ++ci) {
            int j = j0 + wc + ci * 16 + fr;
#pragma unroll
            for (int r = 0; r < 4; ++r) {
                int i = i0 + wr + ri * 16 + q * 4 + r;
                float dv = acc[ri][ci][r];
                DOT[(size_t)i * N + j] = f2bf(dv);
                lmax = fmaxf(lmax, fabsf(dv));
            }
        }
    }
#pragma unroll
    for (int off = 32; off >= 1; off >>= 1) lmax = fmaxf(lmax, __shfl_xor(lmax, off));
    __shared__ float bm[4];
    if (lane == 0) bm[wave] = lmax;
    __syncthreads();
    if (tid == 0)
        blockmax[blockIdx.y * gridDim.x + blockIdx.x] =
            fmaxf(fmaxf(bm[0], bm[1]), fmaxf(bm[2], bm[3]));
}

// ---------------- consts: qs, invS, C from max|dot| ----------------
__global__ __launch_bounds__(256) void setup_consts_k(const float* __restrict__ blockmax,
                                                      float* __restrict__ consts) {
    int t = threadIdx.x;
    float m = fmaxf(fmaxf(blockmax[t], blockmax[t + 256]),
                    fmaxf(blockmax[t + 512], blockmax[t + 768]));
#pragma unroll
    for (int off = 32; off >= 1; off >>= 1) m = fmaxf(m, __shfl_xor(m, off));
    __shared__ float bm[4];
    if ((t & 63) == 0) bm[t >> 6] = m;
    __syncthreads();
    if (t == 0) {
        float maxd = fmaxf(fmaxf(bm[0], bm[1]), fmaxf(bm[2], bm[3]));
        maxd = fmaxf(maxd, 1e-6f);
        consts[0] = 127.0f / maxd;                    // qs (quant scale on dot)
        float invS = 2.0f * LOG2E * maxd / 127.0f;    // dequant step (log2 units)
        consts[1] = invS;
        consts[2] = 127.5f * invS;                    // C
    }
}

// ---------------- quantize DOT -> Q (u8), row-major ----------------
__global__ __launch_bounds__(256) void quant_k(const u16* __restrict__ DOT,
                                               const float* __restrict__ consts,
                                               u8* __restrict__ Q) {
    int idx = blockIdx.x * 256 + threadIdx.x;
    float qs = consts[0];
    ushort8 dv = *((const ushort8*)DOT + idx);
    unsigned o0 = 0, o1 = 0;
#pragma unroll
    for (int e = 0; e < 8; ++e) {
        float r = fmaf(bf2f(dv[e]), -qs, 127.5f);
        r = fminf(fmaxf(r, 0.f), 255.f);
        unsigned qq = (unsigned)(int)(r + 0.5f);
        if (e < 4) o0 |= qq << (8 * e); else o1 |= qq << (8 * (e - 4));
    }
    uivec2 o; o[0] = o0; o[1] = o1;
    *((uivec2*)Q + idx) = o;
}

// ---------------- transposing quantize: DOT -> QT (u8) ----------------
__global__ __launch_bounds__(256) void quantT_k(const u16* __restrict__ DOT,
                                                const float* __restrict__ consts,
                                                u8* __restrict__ QT) {
    __shared__ u16 tile[64][66];
    int bx = blockIdx.x * 64, by = blockIdx.y * 64;
    int t = threadIdx.x;
    int tx = t & 63, ty = t >> 6;
#pragma unroll
    for (int r = 0; r < 64; r += 4)
        tile[r + ty][tx] = DOT[(size_t)(by + r + ty) * N + bx + tx];
    __syncthreads();
    float qs = consts[0];
    int ro = t >> 2, co0 = (t & 3) << 4;
    unsigned w[4] = {0, 0, 0, 0};
#pragma unroll
    for (int k = 0; k < 16; ++k) {
        float v = bf2f(tile[co0 + k][ro]);
        float r = fminf(fmaxf(fmaf(v, -qs, 127.5f), 0.f), 255.f);
        unsigned qq = (unsigned)(int)(r + 0.5f);
        w[k >> 2] |= qq << ((k & 3) * 8);
    }
    uivec4 o; o[0] = w[0]; o[1] = w[1]; o[2] = w[2]; o[3] = w[3];
    *(uivec4*)&QT[(size_t)(bx + ro) * N + by + co0] = o;
}

// ---------------- Wg init: g=0 -> Wg = -y2c ----------------
__global__ __launch_bounds__(256) void init_wg_k(const float* __restrict__ y2c,
                                                 float* __restrict__ Wg) {
    int i = blockIdx.x * 256 + threadIdx.x;
    Wg[i] = -y2c[i];
}

// ---------------- Sinkhorn half-step on u8 Q: one row per wave ---------
// tv_j = Win_j - q_ij*invS ; wout[row] = LA2 - C - LSE_j(tv)
// (potentials kept in W-domain; norms fold in only at the value step)
__global__ __launch_bounds__(256, 4) void sinkhorn_half_q_k(const u8* __restrict__ Q,
                                                            const float* __restrict__ Win,
                                                            const float* __restrict__ consts,
                                                            float* __restrict__ wout) {
    int wid  = (blockIdx.x << 2) | (threadIdx.x >> 6);  // row 0..4095
    int lane = threadIdx.x & 63;
    float invS = consts[1], C = consts[2];
    const u8* row = Q + ((size_t)wid << 12);
    float m = -1e30f, s = 0.f;
#pragma unroll
    for (int c = 0; c < 8; ++c) {
        int j = c * 512 + lane * 8;
        uivec2 qv = *(const uivec2*)(row + j);
        fvec4 w0 = *(const fvec4*)(Win + j);
        fvec4 w1 = *(const fvec4*)(Win + j + 4);
        float tv[8];
#pragma unroll
        for (int e = 0; e < 4; ++e) {
            tv[e]     = fmaf(-invS, (float)((qv[0] >> (8 * e)) & 255u), w0[e]);
            tv[4 + e] = fmaf(-invS, (float)((qv[1] >> (8 * e)) & 255u), w1[e]);
        }
        float mh = fmaxf(fmaxf(max3f(tv[0], tv[1], tv[2]), max3f(tv[3], tv[4], tv[5])),
                         max3f(tv[6], tv[7], m));
        float sh = 0.f;
#pragma unroll
        for (int e = 0; e < 8; ++e) sh += ex2(tv[e] - mh);
        s = fmaf(s, ex2(m - mh), sh);
        m = mh;
    }
#pragma unroll
    for (int off = 32; off >= 1; off >>= 1) {
        float mo = __shfl_xor(m, off);
        float so = __shfl_xor(s, off);
        float mn = fmaxf(m, mo);
        s = fmaf(s, ex2(m - mn), so * ex2(mo - mn));
        m = mn;
    }
    if (lane == 0) wout[wid] = LA2 - C - (m + lg2(s));
}

// ---------------- final g-half FUSED with objective partials ----------
// Per QT-row j: LSE as above (q bytes kept in regs) -> fresh Wg_j = base.
// Then value partial over columns i:
//   p      = exp2(Wf_i + C + Wg_j - q*invS)
//   weight = ln2*(f2_i + g2_j) + VADD,  f2 = Wf + x2c, g2 = base + y2c
__global__ __launch_bounds__(256, 4) void sinkhorn_last_q_k(const u8* __restrict__ QT,
                                                            const float* __restrict__ Wf,
                                                            const float* __restrict__ x2c,
                                                            const float* __restrict__ y2c,
                                                            const float* __restrict__ consts,
                                                            float* __restrict__ partial) {
    int wid  = (blockIdx.x << 2) | (threadIdx.x >> 6);  // QT row j
    int lane = threadIdx.x & 63;
    float invS = consts[1], C = consts[2];
    const u8* row = QT + ((size_t)wid << 12);
    uivec2 qv[8];
    float m = -1e30f, s = 0.f;
#pragma unroll
    for (int c = 0; c < 8; ++c) {
        int j = c * 512 + lane * 8;
        qv[c] = *(const uivec2*)(row + j);
        fvec4 w0 = *(const fvec4*)(Wf + j);
        fvec4 w1 = *(const fvec4*)(Wf + j + 4);
        float tv[8];
#pragma unroll
        for (int e = 0; e < 4; ++e) {
            tv[e]     = fmaf(-invS, (float)((qv[c][0] >> (8 * e)) & 255u), w0[e]);
            tv[4 + e] = fmaf(-invS, (float)((qv[c][1] >> (8 * e)) & 255u), w1[e]);
        }
        float mh = fmaxf(fmaxf(max3f(tv[0], tv[1], tv[2]), max3f(tv[3], tv[4], tv[5])),
                         max3f(tv[6], tv[7], m));
        float sh = 0.f;
#pragma unroll
        for (int e = 0; e < 8; ++e) sh += ex2(tv[e] - mh);
        s = fmaf(s, ex2(m - mh), sh);
        m = mh;
    }
#pragma unroll
    for (int off = 32; off >= 1; off >>= 1) {
        float mo = __shfl_xor(m, off);
        float so = __shfl_xor(s, off);
        float mn = fmaxf(m, mo);
        s = fmaf(s, ex2(m - mn), so * ex2(mo - mn));
        m = mn;
    }
    float base = LA2 - C - (m + lg2(s));   // fresh Wg_j, all lanes
    float g2   = base + y2c[wid];
    float eWG  = base + C;
    float wcol = fmaf(LN2, g2, VADD);
    float local = 0.f;
#pragma unroll
    for (int c = 0; c < 8; ++c) {
        int j = c * 512 + lane * 8;
        fvec4 w0 = *(const fvec4*)(Wf + j);
        fvec4 w1 = *(const fvec4*)(Wf + j + 4);
        fvec4 x0 = *(const fvec4*)(x2c + j);
        fvec4 x1 = *(const fvec4*)(x2c + j + 4);
#pragma unroll
        for (int e = 0; e < 4; ++e) {
            float q0 = (float)((qv[c][0] >> (8 * e)) & 255u);
            float q1 = (float)((qv[c][1] >> (8 * e)) & 255u);
            float p0 = ex2(fmaf(-invS, q0, w0[e]) + eWG);
            float p1 = ex2(fmaf(-invS, q1, w1[e]) + eWG);
            local = fmaf(p0, fmaf(LN2, w0[e] + x0[e], wcol), local);
            local = fmaf(p1, fmaf(LN2, w1[e] + x1[e], wcol), local);
        }
    }
#pragma unroll
    for (int off = 32; off >= 1; off >>= 1) local += __shfl_xor(local, off);
    __shared__ float ps[4];
    if (lane == 0) ps[threadIdx.x >> 6] = local;
    __syncthreads();
    if (threadIdx.x == 0) partial[blockIdx.x] = ps[0] + ps[1] + ps[2] + ps[3];
}

__global__ __launch_bounds__(256) void value_reduce_k(const float* __restrict__ partial,
                                                      float* __restrict__ out) {
    int t = threadIdx.x;
    float s = partial[t] + partial[t + 256] + partial[t + 512] + partial[t + 768];
#pragma unroll
    for (int off = 32; off >= 1; off >>= 1) s += __shfl_xor(s, off);
    __shared__ float fs[4];
    if ((t & 63) == 0) fs[t >> 6] = s;
    __syncthreads();
    if (t == 0) out[0] = fs[0] + fs[1] + fs[2] + fs[3] + 1.0f;
}

extern "C" void kernel_launch(void* const* d_in, const int* in_sizes, int n_in,
                              void* d_out, int out_size, void* d_ws, size_t ws_size,
                              hipStream_t stream) {
    const float* src = (const float*)d_in[0];
    const float* tgt = (const float*)d_in[1];
    float* out = (float*)d_out;

    // workspace: DOT bf16 (32MB) | Qb u8 (16MB) | QTb u8 (16MB) | vectors (~132KB)
    // Xb/Yb (GEMM inputs) alias the QTb region: dead before quantT_k writes QT.
    char* ws = (char*)d_ws;
    u16* DOT = (u16*)ws;
    u8*  Qb  = (u8*)(ws + (32u << 20));
    u8*  QTb = (u8*)(ws + (48u << 20));
    u16* Xb  = (u16*)(ws + (48u << 20));
    u16* Yb  = (u16*)(ws + (52u << 20));
    float* x2c = (float*)(ws + (64u << 20));
    float* y2c = x2c + N;
    float* Wf  = y2c + N;
    float* Wg  = Wf + N;
    float* blockmax = Wg + N;          // 1024 floats
    float* consts   = blockmax + 1024;
    float* partial  = consts + 16;     // 1024 floats

    xy_prep_k<<<N / 4, 256, 0, stream>>>(src, Xb, x2c);
    xy_prep_k<<<N / 4, 256, 0, stream>>>(tgt, Yb, y2c);
    gemm_dot_k<<<dim3(N / 128, N / 128), 256, 0, stream>>>(Xb, Yb, DOT, blockmax);
    setup_consts_k<<<1, 256, 0, stream>>>(blockmax, consts);
    quant_k<<<N * N / (256 * 8), 256, 0, stream>>>(DOT, consts, Qb);
    quantT_k<<<dim3(N / 64, N / 64), 256, 0, stream>>>(DOT, consts, QTb);
    init_wg_k<<<N / 256, 256, 0, stream>>>(y2c, Wg);

    for (int it = 0; it < 100; ++it) {
        sinkhorn_half_q_k<<<N / 4, 256, 0, stream>>>(Qb, Wg, consts, Wf);
        if (it < 99)
            sinkhorn_half_q_k<<<N / 4, 256, 0, stream>>>(QTb, Wf, consts, Wg);
    }

    sinkhorn_last_q_k<<<N / 4, 256, 0, stream>>>(QTb, Wf, x2c, y2c, consts, partial);
    value_reduce_k<<<1, 256, 0, stream>>>(partial, out);
}